// Round 5
// baseline (263.910 us; speedup 1.0000x reference)
//
#include <hip/hip_runtime.h>
#include <hip/hip_bf16.h>
#include <math.h>

#define B_  4
#define S_  2048
#define D_  512
#define H_  8
#define DK_ 64
#define BS_ (B_*S_)

using bf16x8 = __attribute__((ext_vector_type(8))) short;
using f32x4  = __attribute__((ext_vector_type(4))) float;
using f32x16 = __attribute__((ext_vector_type(16))) float;

static __device__ inline unsigned short f2bf(float a) {
  union { __hip_bfloat16 h; unsigned short u; } x;
  x.h = __float2bfloat16(a); return x.u;
}
static __device__ inline float bf16f(unsigned short u) {
  union { unsigned u32; float f; } x; x.u32 = (unsigned)u << 16; return x.f;
}
// HW packed f32->bf16 (RNE), 1 VALU op for 2 values
static __device__ inline unsigned pk2(float a, float b) {
  unsigned r;
  asm("v_cvt_pk_bf16_f32 %0, %1, %2" : "=v"(r) : "v"(a), "v"(b));
  return r;
}
static __device__ inline float ex2(float a) {
  return __builtin_amdgcn_exp2f(a);   // raw v_exp_f32
}

// ---------------------------------------------------------------------------
// MFMA GEMM: C = A @ W + bias, bf16 split-precision (unchanged structure).
// ---------------------------------------------------------------------------
template <int SPLIT, int BF16OUT>
__global__ __launch_bounds__(256) void gemm_mfma_kernel(
    const float* __restrict__ A, const float* __restrict__ W,
    const float* __restrict__ bias, void* __restrict__ Cv) {
  const int bn = blockIdx.x;      // 8
  const int bm = blockIdx.y;      // 64
  const int tid = threadIdx.x;
  const int wv = tid >> 6, lane = tid & 63;
  const int c = lane & 15, g = lane >> 4;

  __shared__ unsigned short As[SPLIT + 1][128][72];
  __shared__ unsigned short Wt[SPLIT + 1][64][72];

  f32x4 acc[2][4];
#pragma unroll
  for (int rt = 0; rt < 2; ++rt)
#pragma unroll
    for (int ds = 0; ds < 4; ++ds) acc[rt][ds] = f32x4{0.f, 0.f, 0.f, 0.f};

  const int arow = tid >> 1, ah = (tid & 1) * 32;
  const int wn = tid & 63, wkg = (tid >> 6) * 16;

  for (int k0 = 0; k0 < D_; k0 += 64) {
    float af[32];
    const float* ag = A + ((size_t)(bm * 128 + arow)) * D_ + k0 + ah;
#pragma unroll
    for (int i = 0; i < 8; ++i) *(float4*)&af[i * 4] = *(const float4*)(ag + i * 4);
    float wf[16];
    const float* wg = W + (size_t)(k0 + wkg) * D_ + bn * 64 + wn;
#pragma unroll
    for (int i = 0; i < 16; ++i) wf[i] = wg[(size_t)i * D_];

    __syncthreads();
#pragma unroll
    for (int grp = 0; grp < 4; ++grp) {
      unsigned h[4], l[4];
#pragma unroll
      for (int p = 0; p < 4; ++p) {
        float f0 = af[grp * 8 + p * 2], f1 = af[grp * 8 + p * 2 + 1];
        h[p] = pk2(f0, f1);
        if constexpr (SPLIT)
          l[p] = pk2(f0 - bf16f((unsigned short)(h[p] & 0xffff)),
                     f1 - bf16f((unsigned short)(h[p] >> 16)));
      }
      uint4 uh; uh.x = h[0]; uh.y = h[1]; uh.z = h[2]; uh.w = h[3];
      *(uint4*)&As[0][arow][ah + grp * 8] = uh;
      if constexpr (SPLIT) {
        uint4 ul; ul.x = l[0]; ul.y = l[1]; ul.z = l[2]; ul.w = l[3];
        *(uint4*)&As[1][arow][ah + grp * 8] = ul;
      }
    }
#pragma unroll
    for (int grp = 0; grp < 2; ++grp) {
      unsigned h[4], l[4];
#pragma unroll
      for (int p = 0; p < 4; ++p) {
        float f0 = wf[grp * 8 + p * 2], f1 = wf[grp * 8 + p * 2 + 1];
        h[p] = pk2(f0, f1);
        if constexpr (SPLIT)
          l[p] = pk2(f0 - bf16f((unsigned short)(h[p] & 0xffff)),
                     f1 - bf16f((unsigned short)(h[p] >> 16)));
      }
      uint4 uh; uh.x = h[0]; uh.y = h[1]; uh.z = h[2]; uh.w = h[3];
      *(uint4*)&Wt[0][wn][wkg + grp * 8] = uh;
      if constexpr (SPLIT) {
        uint4 ul; ul.x = l[0]; ul.y = l[1]; ul.z = l[2]; ul.w = l[3];
        *(uint4*)&Wt[1][wn][wkg + grp * 8] = ul;
      }
    }
    __syncthreads();

#pragma unroll
    for (int ksub = 0; ksub < 2; ++ksub) {
      bf16x8 bh[2], bl[2];
#pragma unroll
      for (int rt = 0; rt < 2; ++rt) {
        bh[rt] = *(const bf16x8*)&As[0][wv * 32 + rt * 16 + c][ksub * 32 + g * 8];
        if constexpr (SPLIT)
          bl[rt] = *(const bf16x8*)&As[1][wv * 32 + rt * 16 + c][ksub * 32 + g * 8];
      }
#pragma unroll
      for (int ds = 0; ds < 4; ++ds) {
        bf16x8 ah_ = *(const bf16x8*)&Wt[0][ds * 16 + c][ksub * 32 + g * 8];
#pragma unroll
        for (int rt = 0; rt < 2; ++rt)
          acc[rt][ds] = __builtin_amdgcn_mfma_f32_16x16x32_bf16(ah_, bh[rt], acc[rt][ds], 0, 0, 0);
        if constexpr (SPLIT) {
          bf16x8 al_ = *(const bf16x8*)&Wt[1][ds * 16 + c][ksub * 32 + g * 8];
#pragma unroll
          for (int rt = 0; rt < 2; ++rt) {
            acc[rt][ds] = __builtin_amdgcn_mfma_f32_16x16x32_bf16(ah_, bl[rt], acc[rt][ds], 0, 0, 0);
            acc[rt][ds] = __builtin_amdgcn_mfma_f32_16x16x32_bf16(al_, bh[rt], acc[rt][ds], 0, 0, 0);
          }
        }
      }
    }
  }

#pragma unroll
  for (int rt = 0; rt < 2; ++rt) {
    const size_t m = (size_t)bm * 128 + wv * 32 + rt * 16 + c;
#pragma unroll
    for (int ds = 0; ds < 4; ++ds) {
      const int n = bn * 64 + ds * 16 + 4 * g;
      float4 bv = *(const float4*)&bias[n];
      float o0 = acc[rt][ds][0] + bv.x, o1 = acc[rt][ds][1] + bv.y;
      float o2 = acc[rt][ds][2] + bv.z, o3 = acc[rt][ds][3] + bv.w;
      if constexpr (BF16OUT) {
        uint2 p; p.x = pk2(o0, o1); p.y = pk2(o2, o3);
        *(uint2*)((unsigned short*)Cv + m * D_ + n) = p;
      } else {
        float4 o; o.x = o0; o.y = o1; o.z = o2; o.w = o3;
        *(float4*)((float*)Cv + m * D_ + n) = o;
      }
    }
  }
}

// ---------------------------------------------------------------------------
// Causal local-window (L=5) softmax pooling; f32 in, bf16 out (scaled).
// ---------------------------------------------------------------------------
__global__ __launch_bounds__(256) void local_pool_kernel(
    const float* __restrict__ x, unsigned short* __restrict__ out,
    float oscale) {
  const int gtid = blockIdx.x * 256 + threadIdx.x;
  const int wave = gtid >> 6;
  const int lane = gtid & 63;
  if (wave >= BS_) return;
  const int b = wave / S_, s = wave % S_;
  const float* xrow = x + ((size_t)b * S_ + s) * D_;
  const int d0 = lane * 8;
  float xi[8];
  *(float4*)&xi[0] = *(const float4*)&xrow[d0];
  *(float4*)&xi[4] = *(const float4*)&xrow[d0 + 4];
  float win[5][8];
  float sc[5];
#pragma unroll
  for (int j = 0; j < 5; ++j) {
    int src = s - 4 + j;
    float part = 0.f;
    if (src >= 0) {
      const float* wr = x + ((size_t)b * S_ + src) * D_;
      *(float4*)&win[j][0] = *(const float4*)&wr[d0];
      *(float4*)&win[j][4] = *(const float4*)&wr[d0 + 4];
#pragma unroll
      for (int t = 0; t < 8; ++t) part += xi[t] * win[j][t];
    } else {
#pragma unroll
      for (int t = 0; t < 8; ++t) win[j][t] = 0.f;
    }
    sc[j] = part;
  }
#pragma unroll
  for (int off = 1; off < 64; off <<= 1) {
#pragma unroll
    for (int j = 0; j < 5; ++j) sc[j] += __shfl_xor(sc[j], off, 64);
  }
  const float scale = 0.04419417382415922f;  // 1/sqrt(512)
  float m = sc[0] * scale;
#pragma unroll
  for (int j = 1; j < 5; ++j) m = fmaxf(m, sc[j] * scale);
  float w[5], lsum = 0.f;
#pragma unroll
  for (int j = 0; j < 5; ++j) { w[j] = expf(sc[j] * scale - m); lsum += w[j]; }
  const float inv = oscale / lsum;
  float o[8] = {};
#pragma unroll
  for (int j = 0; j < 5; ++j)
#pragma unroll
    for (int t = 0; t < 8; ++t) o[t] += w[j] * win[j][t];
  unsigned short* orow = out + ((size_t)b * S_ + s) * D_;
  uint4 pk;
  pk.x = pk2(o[0] * inv, o[1] * inv);
  pk.y = pk2(o[2] * inv, o[3] * inv);
  pk.z = pk2(o[4] * inv, o[5] * inv);
  pk.w = pk2(o[6] * inv, o[7] * inv);
  *(uint4*)&orow[d0] = pk;
}

// ---------------------------------------------------------------------------
// 32x32x16 MFMA flash attention, 2-way KV-split.
// Block = 4 waves: wave (wq, wh) handles q-subtile wq (32 rows of the block's
// 64) over KV half wh (keys [wh*1024, wh*1024+1024), 16 tiles of 64).
// End: LDS combine merges the two halves' (m, l, O) per q-subtile.
// Swapped QK^T (col=q=lane&31, row=key=(reg&3)+8*(reg>>2)+4*hi), exp2-domain
// softmax (q pre-scaled by 0.125*log2e), defer-max THR=10,
// v_permlane32_swap_b32 P-regroup, XOR-swizzled LDS tiles.
// Grid 1024 = 8 XCD * 128; bijective XCD swizzle keeps each (b,h)'s KV on one
// XCD's L2.
// ---------------------------------------------------------------------------
__global__ __launch_bounds__(256, 4) void attn_mfma32_kernel(
    const unsigned short* __restrict__ q, const unsigned short* __restrict__ k,
    const unsigned short* __restrict__ v, float* __restrict__ x) {
  const int bid = (blockIdx.x & 7) * 128 + (blockIdx.x >> 3);  // XCD swizzle
  const int qb = bid & 31;             // 64-row q-block
  const int h  = (bid >> 5) & 7;
  const int b  = bid >> 8;
  const int tid = threadIdx.x;
  const int w = tid >> 6, l = tid & 63;
  const int ql = l & 31, hi = l >> 5;
  const int wq = w & 1, wh = w >> 1;

  __shared__ __align__(16) unsigned short TileMem[4][64 * 64];  // Ks0,Ks1,Vt0,Vt1
  char* KsB = (char*)TileMem[wh];
  char* VtB = (char*)TileMem[2 + wh];

  // Q fragments (B-operand): Qf[f][j] = q[qrow][16f + 8hi + j]
  bf16x8 Qf[4];
  const unsigned short* qg =
      q + ((size_t)b * S_ + qb * 64 + wq * 32 + ql) * D_ + h * 64 + hi * 8;
#pragma unroll
  for (int f = 0; f < 4; ++f) Qf[f] = *(const bf16x8*)(qg + f * 16);

  f32x16 accO[2] = {};           // O^T: [d-tile 32][q]
  float m = -INFINITY, lsum = 0.f;

  // --- staging: 128 threads per half-tile (sh == wh for compute waves) ---
  const int sh = tid >> 7, st = tid & 127;
  const int krow = st >> 1, kco = (st & 1) * 32;   // K: row, 32-ushort col half
  const int vd = st & 63, vg = (st >> 6) & 1;      // V: d-col, 32-key group
  const unsigned short* kg0 =
      k + ((size_t)b * S_ + sh * 1024 + krow) * D_ + h * 64 + kco;
  const unsigned short* vg0 =
      v + ((size_t)b * S_ + sh * 1024 + vg * 32) * D_ + h * 64 + vd;
  char* KsS = (char*)TileMem[sh];
  char* VtS = (char*)TileMem[2 + sh];
  int kaddr[4], vaddr[4];
#pragma unroll
  for (int i = 0; i < 4; ++i) {
    kaddr[i] = (krow * 128 + kco * 2 + i * 16) ^ ((krow & 7) << 4);
    vaddr[i] = (vd * 128 + vg * 64 + i * 16) ^ ((vd & 7) << 4);
  }

  // prefetch tile 0 (keys packed pairwise along the Vt row)
  uint4 rk[4];
  unsigned rvp[16];
#pragma unroll
  for (int i = 0; i < 4; ++i) rk[i] = *(const uint4*)(kg0 + i * 8);
#pragma unroll
  for (int i = 0; i < 16; ++i) {
    unsigned lo = vg0[(size_t)(2 * i) * D_];
    unsigned hs = vg0[(size_t)(2 * i + 1) * D_];
    rvp[i] = lo | (hs << 16);
  }

  for (int kt = 0; kt < 16; ++kt) {
    __syncthreads();                      // prev compute done reading LDS
#pragma unroll
    for (int i = 0; i < 4; ++i) *(uint4*)(KsS + kaddr[i]) = rk[i];
#pragma unroll
    for (int i = 0; i < 4; ++i) {
      uint4 t_;
      t_.x = rvp[4 * i]; t_.y = rvp[4 * i + 1];
      t_.z = rvp[4 * i + 2]; t_.w = rvp[4 * i + 3];
      *(uint4*)(VtS + vaddr[i]) = t_;
    }
    __syncthreads();
    if (kt + 1 < 16) {                    // prefetch next tile
      const size_t koff = (size_t)(kt + 1) * 64 * D_;
#pragma unroll
      for (int i = 0; i < 4; ++i) rk[i] = *(const uint4*)(kg0 + koff + i * 8);
#pragma unroll
      for (int i = 0; i < 16; ++i) {
        unsigned lo = vg0[koff + (size_t)(2 * i) * D_];
        unsigned hs = vg0[koff + (size_t)(2 * i + 1) * D_];
        rvp[i] = lo | (hs << 16);
      }
    }

    // ---- QK^T: two 32-key subtiles ----
    f32x16 sA = {}, sB = {};
    __builtin_amdgcn_s_setprio(1);
#pragma unroll
    for (int f = 0; f < 4; ++f) {
      bf16x8 a0 = *(const bf16x8*)(KsB + ((ql * 128 + f * 32 + hi * 16) ^ ((ql & 7) << 4)));
      bf16x8 a1 = *(const bf16x8*)(KsB + (((ql + 32) * 128 + f * 32 + hi * 16) ^ ((ql & 7) << 4)));
      sA = __builtin_amdgcn_mfma_f32_32x32x16_bf16(a0, Qf[f], sA, 0, 0, 0);
      sB = __builtin_amdgcn_mfma_f32_32x32x16_bf16(a1, Qf[f], sB, 0, 0, 0);
    }
    __builtin_amdgcn_s_setprio(0);

    // ---- online softmax (exp2 domain), tree reduce, defer-max THR=10 ----
    float mx[8];
#pragma unroll
    for (int r = 0; r < 8; ++r)
      mx[r] = fmaxf(fmaxf(sA[r], sA[r + 8]), fmaxf(sB[r], sB[r + 8]));
#pragma unroll
    for (int o = 4; o; o >>= 1)
#pragma unroll
      for (int r = 0; r < 4; ++r)
        if (r < o) mx[r] = fmaxf(mx[r], mx[r + o]);
    float mt = fmaxf(mx[0], __shfl_xor(mx[0], 32, 64));
    if (!__all(mt <= m + 10.0f)) {
      const float mn = fmaxf(m, mt);
      const float corr = ex2(m - mn);
      m = mn;
      lsum *= corr;
#pragma unroll
      for (int dt = 0; dt < 2; ++dt)
#pragma unroll
        for (int r = 0; r < 16; ++r) accO[dt][r] *= corr;
    }
    float pA[16], pB[16], tsum[16];
#pragma unroll
    for (int r = 0; r < 16; ++r) {
      pA[r] = ex2(sA[r] - m);
      pB[r] = ex2(sB[r] - m);
      tsum[r] = pA[r] + pB[r];
    }
#pragma unroll
    for (int o = 8; o; o >>= 1)
#pragma unroll
      for (int r = 0; r < 8; ++r)
        if (r < o) tsum[r] += tsum[r + o];
    lsum += tsum[0];

    // ---- pack P -> bf16 (HW cvt_pk) ----
    unsigned WA[8], WB[8];
#pragma unroll
    for (int t = 0; t < 4; ++t) {
      WA[2 * t]     = pk2(pA[4 * t], pA[4 * t + 1]);
      WA[2 * t + 1] = pk2(pA[4 * t + 2], pA[4 * t + 3]);
      WB[2 * t]     = pk2(pB[4 * t], pB[4 * t + 1]);
      WB[2 * t + 1] = pk2(pB[4 * t + 2], pB[4 * t + 3]);
    }

    // ---- PV: 4 key-chunks x 2 d-tiles ----
#pragma unroll
    for (int kc = 0; kc < 4; ++kc) {
      unsigned w0 = (kc < 2) ? WA[(kc & 1) * 4 + 0] : WB[(kc & 1) * 4 + 0];
      unsigned w1 = (kc < 2) ? WA[(kc & 1) * 4 + 1] : WB[(kc & 1) * 4 + 1];
      unsigned w2 = (kc < 2) ? WA[(kc & 1) * 4 + 2] : WB[(kc & 1) * 4 + 2];
      unsigned w3 = (kc < 2) ? WA[(kc & 1) * 4 + 3] : WB[(kc & 1) * 4 + 3];
      asm volatile("v_permlane32_swap_b32 %0, %1" : "+v"(w0), "+v"(w2));
      asm volatile("v_permlane32_swap_b32 %0, %1" : "+v"(w1), "+v"(w3));
      union { unsigned u[4]; bf16x8 v8; } pb;
      pb.u[0] = w0; pb.u[1] = w1; pb.u[2] = w2; pb.u[3] = w3;
      __builtin_amdgcn_s_setprio(1);
#pragma unroll
      for (int dt = 0; dt < 2; ++dt) {
        const int vrow = dt * 32 + ql;
        bf16x8 va = *(const bf16x8*)(VtB + ((vrow * 128 + kc * 32 + hi * 16) ^ ((ql & 7) << 4)));
        accO[dt] = __builtin_amdgcn_mfma_f32_32x32x16_bf16(va, pb.v8, accO[dt], 0, 0, 0);
      }
      __builtin_amdgcn_s_setprio(0);
    }
  }

  // ---- cross-wave combine (halves share q-subtile) ----
  float lw = lsum + __shfl_xor(lsum, 32, 64);
  __syncthreads();                        // all waves done with tiles
  float* cb = (float*)TileMem + (size_t)wq * 2176 + (size_t)l * 34;
  if (wh == 1) {
#pragma unroll
    for (int dt = 0; dt < 2; ++dt)
#pragma unroll
      for (int r = 0; r < 16; ++r) cb[dt * 16 + r] = accO[dt][r];
    cb[32] = m; cb[33] = lw;
  }
  __syncthreads();
  if (wh == 0) {
    const float m1 = cb[32], l1 = cb[33];
    const float mn = fmaxf(m, m1);
    const float a0 = ex2(m - mn), a1 = ex2(m1 - mn);
    const float inv = 1.f / (lw * a0 + l1 * a1);
    float* xrow = x + ((size_t)b * S_ + qb * 64 + wq * 32 + ql) * D_ + h * 64;
#pragma unroll
    for (int dt = 0; dt < 2; ++dt)
#pragma unroll
      for (int g0 = 0; g0 < 4; ++g0) {
        float4 o;
        o.x = (accO[dt][4 * g0 + 0] * a0 + cb[dt * 16 + 4 * g0 + 0] * a1) * inv;
        o.y = (accO[dt][4 * g0 + 1] * a0 + cb[dt * 16 + 4 * g0 + 1] * a1) * inv;
        o.z = (accO[dt][4 * g0 + 2] * a0 + cb[dt * 16 + 4 * g0 + 2] * a1) * inv;
        o.w = (accO[dt][4 * g0 + 3] * a0 + cb[dt * 16 + 4 * g0 + 3] * a1) * inv;
        *(float4*)&xrow[dt * 32 + hi * 4 + g0 * 8] = o;
      }
  }
}

// ---------------------------------------------------------------------------
extern "C" void kernel_launch(void* const* d_in, const int* in_sizes, int n_in,
                              void* d_out, int out_size, void* d_ws, size_t ws_size,
                              hipStream_t stream) {
  const float* query = (const float*)d_in[0];
  const float* key   = (const float*)d_in[1];
  const float* value = (const float*)d_in[2];
  const float* W_fk = (const float*)d_in[4];
  const float* b_fk = (const float*)d_in[5];
  const float* W0   = (const float*)d_in[6];
  const float* b0   = (const float*)d_in[7];
  const float* Wout = (const float*)d_in[8];
  const float* bout = (const float*)d_in[9];
  float* out = (float*)d_out;

  char* ws = (char*)d_ws;
  float* kfk_f32   = (float*)ws;                       // 16MB @ 0 (later q_bf16)
  float* x_f32     = (float*)(ws + (16u << 20));       // 16MB @ 16MB
  unsigned short* k_bf16 = (unsigned short*)(ws + (32u << 20));  // 8MB @ 32MB
  unsigned short* v_bf16 = (unsigned short*)(ws + (40u << 20));  // 8MB @ 40MB
  unsigned short* q_bf16 = (unsigned short*)ws;        // overlays kfk after use

  dim3 mgrid(D_ / 64, BS_ / 128);
  dim3 pgrid(BS_ * 64 / 256);
  // 1/sqrt(dk) * log2(e): softmax runs in exp2 domain
  const float qscale = 0.125f * 1.4426950408889634f;

  gemm_mfma_kernel<1, 0><<<mgrid, 256, 0, stream>>>(key, W_fk, b_fk, kfk_f32);
  local_pool_kernel<<<pgrid, 256, 0, stream>>>(kfk_f32, k_bf16, 1.0f);
  gemm_mfma_kernel<0, 1><<<mgrid, 256, 0, stream>>>(value, W0, b0, v_bf16);
  local_pool_kernel<<<pgrid, 256, 0, stream>>>(query, q_bf16, qscale);
  attn_mfma32_kernel<<<dim3(B_ * H_ * (S_ / 64)), 256, 0, stream>>>(q_bf16, k_bf16, v_bf16, x_f32);
  gemm_mfma_kernel<1, 0><<<mgrid, 256, 0, stream>>>(x_f32, Wout, bout, out);
}

// Round 6
// 205.971 us; speedup vs baseline: 1.2813x; 1.2813x over previous
//
#include <hip/hip_runtime.h>
#include <hip/hip_bf16.h>
#include <math.h>

#define B_  4
#define S_  2048
#define D_  512
#define H_  8
#define DK_ 64
#define BS_ (B_*S_)

using bf16x8 = __attribute__((ext_vector_type(8))) short;
using f32x4  = __attribute__((ext_vector_type(4))) float;
using f32x16 = __attribute__((ext_vector_type(16))) float;

typedef const __attribute__((address_space(1))) unsigned int gu32;
typedef __attribute__((address_space(3))) unsigned int lu32;

static __device__ inline unsigned short f2bf(float a) {
  union { __hip_bfloat16 h; unsigned short u; } x;
  x.h = __float2bfloat16(a); return x.u;
}
static __device__ inline float bf16f(unsigned short u) {
  union { unsigned u32; float f; } x; x.u32 = (unsigned)u << 16; return x.f;
}
// HW packed f32->bf16 (RNE), 1 VALU op for 2 values
static __device__ inline unsigned pk2(float a, float b) {
  unsigned r;
  asm("v_cvt_pk_bf16_f32 %0, %1, %2" : "=v"(r) : "v"(a), "v"(b));
  return r;
}
static __device__ inline float ex2(float a) {
  return __builtin_amdgcn_exp2f(a);   // raw v_exp_f32
}

// ---------------------------------------------------------------------------
// MFMA GEMM: C = A @ W + bias, bf16 split-precision (unchanged).
// ---------------------------------------------------------------------------
template <int SPLIT, int BF16OUT>
__global__ __launch_bounds__(256) void gemm_mfma_kernel(
    const float* __restrict__ A, const float* __restrict__ W,
    const float* __restrict__ bias, void* __restrict__ Cv) {
  const int bn = blockIdx.x;      // 8
  const int bm = blockIdx.y;      // 64
  const int tid = threadIdx.x;
  const int wv = tid >> 6, lane = tid & 63;
  const int c = lane & 15, g = lane >> 4;

  __shared__ unsigned short As[SPLIT + 1][128][72];
  __shared__ unsigned short Wt[SPLIT + 1][64][72];

  f32x4 acc[2][4];
#pragma unroll
  for (int rt = 0; rt < 2; ++rt)
#pragma unroll
    for (int ds = 0; ds < 4; ++ds) acc[rt][ds] = f32x4{0.f, 0.f, 0.f, 0.f};

  const int arow = tid >> 1, ah = (tid & 1) * 32;
  const int wn = tid & 63, wkg = (tid >> 6) * 16;

  for (int k0 = 0; k0 < D_; k0 += 64) {
    float af[32];
    const float* ag = A + ((size_t)(bm * 128 + arow)) * D_ + k0 + ah;
#pragma unroll
    for (int i = 0; i < 8; ++i) *(float4*)&af[i * 4] = *(const float4*)(ag + i * 4);
    float wf[16];
    const float* wg = W + (size_t)(k0 + wkg) * D_ + bn * 64 + wn;
#pragma unroll
    for (int i = 0; i < 16; ++i) wf[i] = wg[(size_t)i * D_];

    __syncthreads();
#pragma unroll
    for (int grp = 0; grp < 4; ++grp) {
      unsigned h[4], l[4];
#pragma unroll
      for (int p = 0; p < 4; ++p) {
        float f0 = af[grp * 8 + p * 2], f1 = af[grp * 8 + p * 2 + 1];
        h[p] = pk2(f0, f1);
        if constexpr (SPLIT)
          l[p] = pk2(f0 - bf16f((unsigned short)(h[p] & 0xffff)),
                     f1 - bf16f((unsigned short)(h[p] >> 16)));
      }
      uint4 uh; uh.x = h[0]; uh.y = h[1]; uh.z = h[2]; uh.w = h[3];
      *(uint4*)&As[0][arow][ah + grp * 8] = uh;
      if constexpr (SPLIT) {
        uint4 ul; ul.x = l[0]; ul.y = l[1]; ul.z = l[2]; ul.w = l[3];
        *(uint4*)&As[1][arow][ah + grp * 8] = ul;
      }
    }
#pragma unroll
    for (int grp = 0; grp < 2; ++grp) {
      unsigned h[4], l[4];
#pragma unroll
      for (int p = 0; p < 4; ++p) {
        float f0 = wf[grp * 8 + p * 2], f1 = wf[grp * 8 + p * 2 + 1];
        h[p] = pk2(f0, f1);
        if constexpr (SPLIT)
          l[p] = pk2(f0 - bf16f((unsigned short)(h[p] & 0xffff)),
                     f1 - bf16f((unsigned short)(h[p] >> 16)));
      }
      uint4 uh; uh.x = h[0]; uh.y = h[1]; uh.z = h[2]; uh.w = h[3];
      *(uint4*)&Wt[0][wn][wkg + grp * 8] = uh;
      if constexpr (SPLIT) {
        uint4 ul; ul.x = l[0]; ul.y = l[1]; ul.z = l[2]; ul.w = l[3];
        *(uint4*)&Wt[1][wn][wkg + grp * 8] = ul;
      }
    }
    __syncthreads();

#pragma unroll
    for (int ksub = 0; ksub < 2; ++ksub) {
      bf16x8 bh[2], bl[2];
#pragma unroll
      for (int rt = 0; rt < 2; ++rt) {
        bh[rt] = *(const bf16x8*)&As[0][wv * 32 + rt * 16 + c][ksub * 32 + g * 8];
        if constexpr (SPLIT)
          bl[rt] = *(const bf16x8*)&As[1][wv * 32 + rt * 16 + c][ksub * 32 + g * 8];
      }
#pragma unroll
      for (int ds = 0; ds < 4; ++ds) {
        bf16x8 ah_ = *(const bf16x8*)&Wt[0][ds * 16 + c][ksub * 32 + g * 8];
#pragma unroll
        for (int rt = 0; rt < 2; ++rt)
          acc[rt][ds] = __builtin_amdgcn_mfma_f32_16x16x32_bf16(ah_, bh[rt], acc[rt][ds], 0, 0, 0);
        if constexpr (SPLIT) {
          bf16x8 al_ = *(const bf16x8*)&Wt[1][ds * 16 + c][ksub * 32 + g * 8];
#pragma unroll
          for (int rt = 0; rt < 2; ++rt) {
            acc[rt][ds] = __builtin_amdgcn_mfma_f32_16x16x32_bf16(ah_, bl[rt], acc[rt][ds], 0, 0, 0);
            acc[rt][ds] = __builtin_amdgcn_mfma_f32_16x16x32_bf16(al_, bh[rt], acc[rt][ds], 0, 0, 0);
          }
        }
      }
    }
  }

#pragma unroll
  for (int rt = 0; rt < 2; ++rt) {
    const size_t m = (size_t)bm * 128 + wv * 32 + rt * 16 + c;
#pragma unroll
    for (int ds = 0; ds < 4; ++ds) {
      const int n = bn * 64 + ds * 16 + 4 * g;
      float4 bv = *(const float4*)&bias[n];
      float o0 = acc[rt][ds][0] + bv.x, o1 = acc[rt][ds][1] + bv.y;
      float o2 = acc[rt][ds][2] + bv.z, o3 = acc[rt][ds][3] + bv.w;
      if constexpr (BF16OUT) {
        uint2 p; p.x = pk2(o0, o1); p.y = pk2(o2, o3);
        *(uint2*)((unsigned short*)Cv + m * D_ + n) = p;
      } else {
        float4 o; o.x = o0; o.y = o1; o.z = o2; o.w = o3;
        *(float4*)((float*)Cv + m * D_ + n) = o;
      }
    }
  }
}

// ---------------------------------------------------------------------------
// Causal local-window (L=5) softmax pooling; f32 in, bf16 out (scaled).
// ---------------------------------------------------------------------------
__global__ __launch_bounds__(256) void local_pool_kernel(
    const float* __restrict__ x, unsigned short* __restrict__ out,
    float oscale) {
  const int gtid = blockIdx.x * 256 + threadIdx.x;
  const int wave = gtid >> 6;
  const int lane = gtid & 63;
  if (wave >= BS_) return;
  const int b = wave / S_, s = wave % S_;
  const float* xrow = x + ((size_t)b * S_ + s) * D_;
  const int d0 = lane * 8;
  float xi[8];
  *(float4*)&xi[0] = *(const float4*)&xrow[d0];
  *(float4*)&xi[4] = *(const float4*)&xrow[d0 + 4];
  float win[5][8];
  float sc[5];
#pragma unroll
  for (int j = 0; j < 5; ++j) {
    int src = s - 4 + j;
    float part = 0.f;
    if (src >= 0) {
      const float* wr = x + ((size_t)b * S_ + src) * D_;
      *(float4*)&win[j][0] = *(const float4*)&wr[d0];
      *(float4*)&win[j][4] = *(const float4*)&wr[d0 + 4];
#pragma unroll
      for (int t = 0; t < 8; ++t) part += xi[t] * win[j][t];
    } else {
#pragma unroll
      for (int t = 0; t < 8; ++t) win[j][t] = 0.f;
    }
    sc[j] = part;
  }
#pragma unroll
  for (int off = 1; off < 64; off <<= 1) {
#pragma unroll
    for (int j = 0; j < 5; ++j) sc[j] += __shfl_xor(sc[j], off, 64);
  }
  const float scale = 0.04419417382415922f;  // 1/sqrt(512)
  float m = sc[0] * scale;
#pragma unroll
  for (int j = 1; j < 5; ++j) m = fmaxf(m, sc[j] * scale);
  float w[5], lsum = 0.f;
#pragma unroll
  for (int j = 0; j < 5; ++j) { w[j] = expf(sc[j] * scale - m); lsum += w[j]; }
  const float inv = oscale / lsum;
  float o[8] = {};
#pragma unroll
  for (int j = 0; j < 5; ++j)
#pragma unroll
    for (int t = 0; t < 8; ++t) o[t] += w[j] * win[j][t];
  unsigned short* orow = out + ((size_t)b * S_ + s) * D_;
  uint4 pk;
  pk.x = pk2(o[0] * inv, o[1] * inv);
  pk.y = pk2(o[2] * inv, o[3] * inv);
  pk.z = pk2(o[4] * inv, o[5] * inv);
  pk.w = pk2(o[6] * inv, o[7] * inv);
  *(uint4*)&orow[d0] = pk;
}

// ---------------------------------------------------------------------------
// 32x32x16 MFMA flash attention, 2-way KV-split, low register pressure.
// Block = 4 waves: wave (wq, wh) = q-subtile wq over KV half wh (16 tiles).
// K staged via global_load_lds (async, no VGPR): LDS dest is LINEAR
// (base + lane*16); the XOR swizzle is applied to the per-lane GLOBAL source
// chunk instead (rule: linear dest + inverse-swizzled source + XOR on read).
// Lane l covers row r = 8j + (l>>3) (within its wave's 32-row range), LDS
// chunk c = l&7; since (row&7) == l>>3, it loads global chunk (l&7)^(l>>3),
// so LDS chunk c of row r holds global chunk c^(r&7) -- exactly what the
// XOR-swizzled ds_read expects.
// V prefetched as 16 packed dwords/thread (transpose in regs), ds_write b128.
// Softmax: exp2-domain (q pre-scaled 0.125*log2e), tree max, defer-max
// THR=10, fused exp->cvt_pk pack (no pA/pB arrays). PV via permlane32_swap.
// ---------------------------------------------------------------------------
__global__ __launch_bounds__(256, 4) void attn_mfma32_kernel(
    const unsigned short* __restrict__ q, const unsigned short* __restrict__ k,
    const unsigned short* __restrict__ v, float* __restrict__ x) {
  const int bid = (blockIdx.x & 7) * 128 + (blockIdx.x >> 3);  // XCD swizzle
  const int qb = bid & 31;             // 64-row q-block
  const int h  = (bid >> 5) & 7;
  const int b  = bid >> 8;
  const int tid = threadIdx.x;
  const int w = tid >> 6, l = tid & 63;
  const int ql = l & 31, hi = l >> 5;
  const int wq = w & 1, wh = w >> 1;

  __shared__ __align__(16) unsigned short TileMem[4][64 * 64];  // K0,K1,V0,V1
  char* KsB = (char*)TileMem[wh];
  char* VtB = (char*)TileMem[2 + wh];

  // Q fragments (B-operand): Qf[f][j] = q[qrow][16f + 8hi + j]
  bf16x8 Qf[4];
  {
    const unsigned short* qg =
        q + ((size_t)b * S_ + qb * 64 + wq * 32 + ql) * D_ + h * 64 + hi * 8;
#pragma unroll
    for (int f = 0; f < 4; ++f) Qf[f] = *(const bf16x8*)(qg + f * 16);
  }

  f32x16 accO[2] = {};           // O^T: [d-tile 32][q]
  float m = -INFINITY, lsum = 0.f;

  // ---- K staging (async): wave (wh, wq) stages rows wq*32..+31 of half wh ----
  const int lr8 = l >> 3, lc = l & 7;
  const unsigned short* kgl =
      k + ((size_t)b * S_ + wh * 1024 + wq * 32 + lr8) * D_ + h * 64 + ((lc ^ lr8) << 3);
  char* ldsK = (char*)TileMem[wh] + wq * 4096;   // + j*1024 per instr

  // ---- V staging: 128 threads per half (sh == wh for the half's waves) ----
  const int sh = tid >> 7, st = tid & 127;
  const int vd = st & 63, vg2 = (st >> 6) & 1;
  const unsigned short* vg0 =
      v + ((size_t)b * S_ + sh * 1024 + vg2 * 32) * D_ + h * 64 + vd;
  char* VtS = (char*)TileMem[2 + sh];
  const int vb0 = vd * 128 + vg2 * 64, vmask = (vd & 7) << 4;

  // prefetch V tile 0 (pairs of keys packed into dwords)
  unsigned rvp[16];
#pragma unroll
  for (int i = 0; i < 16; ++i) {
    unsigned lo = vg0[(size_t)(2 * i) * D_];
    unsigned hs = vg0[(size_t)(2 * i + 1) * D_];
    rvp[i] = lo | (hs << 16);
  }

  for (int kt = 0; kt < 16; ++kt) {
    __syncthreads();                      // prev compute done reading LDS
    {  // K: async global->LDS, linear dest, pre-swizzled source
      const unsigned short* kp = kgl + (size_t)kt * 64 * D_;
#pragma unroll
      for (int j = 0; j < 4; ++j)
        __builtin_amdgcn_global_load_lds((gu32*)(kp + (size_t)j * 8 * D_),
                                         (lu32*)(ldsK + j * 1024), 16, 0, 0);
    }
    // V: write prefetched regs (XOR-swizzled ds_write_b128)
#pragma unroll
    for (int i = 0; i < 4; ++i) {
      uint4 t_;
      t_.x = rvp[4 * i]; t_.y = rvp[4 * i + 1];
      t_.z = rvp[4 * i + 2]; t_.w = rvp[4 * i + 3];
      *(uint4*)(VtS + ((vb0 + i * 16) ^ vmask)) = t_;
    }
    __syncthreads();                      // drains vmcnt (K) + lgkm (V)
    if (kt + 1 < 16) {                    // prefetch next V tile
      const size_t koff = (size_t)(kt + 1) * 64 * D_;
#pragma unroll
      for (int i = 0; i < 16; ++i) {
        unsigned lo = vg0[koff + (size_t)(2 * i) * D_];
        unsigned hs = vg0[koff + (size_t)(2 * i + 1) * D_];
        rvp[i] = lo | (hs << 16);
      }
    }

    // ---- QK^T: two 32-key subtiles ----
    f32x16 sA = {}, sB = {};
    __builtin_amdgcn_s_setprio(1);
#pragma unroll
    for (int f = 0; f < 4; ++f) {
      bf16x8 a0 = *(const bf16x8*)(KsB + ((ql * 128 + f * 32 + hi * 16) ^ ((ql & 7) << 4)));
      bf16x8 a1 = *(const bf16x8*)(KsB + (((ql + 32) * 128 + f * 32 + hi * 16) ^ ((ql & 7) << 4)));
      sA = __builtin_amdgcn_mfma_f32_32x32x16_bf16(a0, Qf[f], sA, 0, 0, 0);
      sB = __builtin_amdgcn_mfma_f32_32x32x16_bf16(a1, Qf[f], sB, 0, 0, 0);
    }
    __builtin_amdgcn_s_setprio(0);

    // ---- tree max, defer-max THR=10 ----
    float mx[8];
#pragma unroll
    for (int r = 0; r < 8; ++r)
      mx[r] = fmaxf(fmaxf(sA[r], sA[r + 8]), fmaxf(sB[r], sB[r + 8]));
    mx[0] = fmaxf(mx[0], mx[4]); mx[1] = fmaxf(mx[1], mx[5]);
    mx[2] = fmaxf(mx[2], mx[6]); mx[3] = fmaxf(mx[3], mx[7]);
    mx[0] = fmaxf(fmaxf(mx[0], mx[1]), fmaxf(mx[2], mx[3]));
    const float mt = fmaxf(mx[0], __shfl_xor(mx[0], 32, 64));
    if (!__all(mt <= m + 10.0f)) {
      const float mn = fmaxf(m, mt);
      const float corr = ex2(m - mn);
      m = mn;
      lsum *= corr;
#pragma unroll
      for (int dt = 0; dt < 2; ++dt)
#pragma unroll
        for (int r = 0; r < 16; ++r) accO[dt][r] *= corr;
    }

    // ---- fused exp2 -> pack -> pairwise sum (no pA/pB arrays) ----
    unsigned WA[8], WB[8];
    float s0 = 0.f, s1 = 0.f, s2 = 0.f, s3 = 0.f;
#pragma unroll
    for (int t = 0; t < 4; ++t) {
      float a0 = ex2(sA[4 * t + 0] - m), a1 = ex2(sA[4 * t + 1] - m);
      float a2 = ex2(sA[4 * t + 2] - m), a3 = ex2(sA[4 * t + 3] - m);
      WA[2 * t] = pk2(a0, a1); WA[2 * t + 1] = pk2(a2, a3);
      s0 += a0 + a1; s1 += a2 + a3;
      float b0 = ex2(sB[4 * t + 0] - m), b1 = ex2(sB[4 * t + 1] - m);
      float b2 = ex2(sB[4 * t + 2] - m), b3 = ex2(sB[4 * t + 3] - m);
      WB[2 * t] = pk2(b0, b1); WB[2 * t + 1] = pk2(b2, b3);
      s2 += b0 + b1; s3 += b2 + b3;
    }
    lsum += (s0 + s1) + (s2 + s3);

    // ---- PV: 4 key-chunks x 2 d-tiles ----
#pragma unroll
    for (int kc = 0; kc < 4; ++kc) {
      unsigned w0 = (kc < 2) ? WA[(kc & 1) * 4 + 0] : WB[(kc & 1) * 4 + 0];
      unsigned w1 = (kc < 2) ? WA[(kc & 1) * 4 + 1] : WB[(kc & 1) * 4 + 1];
      unsigned w2 = (kc < 2) ? WA[(kc & 1) * 4 + 2] : WB[(kc & 1) * 4 + 2];
      unsigned w3 = (kc < 2) ? WA[(kc & 1) * 4 + 3] : WB[(kc & 1) * 4 + 3];
      asm volatile("v_permlane32_swap_b32 %0, %1" : "+v"(w0), "+v"(w2));
      asm volatile("v_permlane32_swap_b32 %0, %1" : "+v"(w1), "+v"(w3));
      union { unsigned u[4]; bf16x8 v8; } pb;
      pb.u[0] = w0; pb.u[1] = w1; pb.u[2] = w2; pb.u[3] = w3;
      __builtin_amdgcn_s_setprio(1);
#pragma unroll
      for (int dt = 0; dt < 2; ++dt) {
        const int vrow = dt * 32 + ql;
        bf16x8 va = *(const bf16x8*)(VtB + ((vrow * 128 + kc * 32 + hi * 16) ^ ((ql & 7) << 4)));
        accO[dt] = __builtin_amdgcn_mfma_f32_32x32x16_bf16(va, pb.v8, accO[dt], 0, 0, 0);
      }
      __builtin_amdgcn_s_setprio(0);
    }
  }

  // ---- cross-wave combine (halves share q-subtile) ----
  float lw = lsum + __shfl_xor(lsum, 32, 64);
  __syncthreads();                        // all waves done with tiles
  float* cb = (float*)TileMem + (size_t)wq * 2176 + (size_t)l * 34;
  if (wh == 1) {
#pragma unroll
    for (int dt = 0; dt < 2; ++dt)
#pragma unroll
      for (int r = 0; r < 16; ++r) cb[dt * 16 + r] = accO[dt][r];
    cb[32] = m; cb[33] = lw;
  }
  __syncthreads();
  if (wh == 0) {
    const float m1 = cb[32], l1 = cb[33];
    const float mn = fmaxf(m, m1);
    const float a0 = ex2(m - mn), a1 = ex2(m1 - mn);
    const float inv = 1.f / (lw * a0 + l1 * a1);
    float* xrow = x + ((size_t)b * S_ + qb * 64 + wq * 32 + ql) * D_ + h * 64;
#pragma unroll
    for (int dt = 0; dt < 2; ++dt)
#pragma unroll
      for (int g0 = 0; g0 < 4; ++g0) {
        float4 o;
        o.x = (accO[dt][4 * g0 + 0] * a0 + cb[dt * 16 + 4 * g0 + 0] * a1) * inv;
        o.y = (accO[dt][4 * g0 + 1] * a0 + cb[dt * 16 + 4 * g0 + 1] * a1) * inv;
        o.z = (accO[dt][4 * g0 + 2] * a0 + cb[dt * 16 + 4 * g0 + 2] * a1) * inv;
        o.w = (accO[dt][4 * g0 + 3] * a0 + cb[dt * 16 + 4 * g0 + 3] * a1) * inv;
        *(float4*)&xrow[dt * 32 + hi * 4 + g0 * 8] = o;
      }
  }
}

// ---------------------------------------------------------------------------
extern "C" void kernel_launch(void* const* d_in, const int* in_sizes, int n_in,
                              void* d_out, int out_size, void* d_ws, size_t ws_size,
                              hipStream_t stream) {
  const float* query = (const float*)d_in[0];
  const float* key   = (const float*)d_in[1];
  const float* value = (const float*)d_in[2];
  const float* W_fk = (const float*)d_in[4];
  const float* b_fk = (const float*)d_in[5];
  const float* W0   = (const float*)d_in[6];
  const float* b0   = (const float*)d_in[7];
  const float* Wout = (const float*)d_in[8];
  const float* bout = (const float*)d_in[9];
  float* out = (float*)d_out;

  char* ws = (char*)d_ws;
  float* kfk_f32   = (float*)ws;                       // 16MB @ 0 (later q_bf16)
  float* x_f32     = (float*)(ws + (16u << 20));       // 16MB @ 16MB
  unsigned short* k_bf16 = (unsigned short*)(ws + (32u << 20));  // 8MB @ 32MB
  unsigned short* v_bf16 = (unsigned short*)(ws + (40u << 20));  // 8MB @ 40MB
  unsigned short* q_bf16 = (unsigned short*)ws;        // overlays kfk after use

  dim3 mgrid(D_ / 64, BS_ / 128);
  dim3 pgrid(BS_ * 64 / 256);
  // 1/sqrt(dk) * log2(e): softmax runs in exp2 domain
  const float qscale = 0.125f * 1.4426950408889634f;

  gemm_mfma_kernel<1, 0><<<mgrid, 256, 0, stream>>>(key, W_fk, b_fk, kfk_f32);
  local_pool_kernel<<<pgrid, 256, 0, stream>>>(kfk_f32, k_bf16, 1.0f);
  gemm_mfma_kernel<0, 1><<<mgrid, 256, 0, stream>>>(value, W0, b0, v_bf16);
  local_pool_kernel<<<pgrid, 256, 0, stream>>>(query, q_bf16, qscale);
  attn_mfma32_kernel<<<dim3(B_ * H_ * (S_ / 64)), 256, 0, stream>>>(q_bf16, k_bf16, v_bf16, x_f32);
  gemm_mfma_kernel<1, 0><<<mgrid, 256, 0, stream>>>(x_f32, Wout, bout, out);
}

// Round 7
// 183.882 us; speedup vs baseline: 1.4352x; 1.1201x over previous
//
#include <hip/hip_runtime.h>
#include <hip/hip_bf16.h>
#include <math.h>

#define B_  4
#define S_  2048
#define D_  512
#define H_  8
#define DK_ 64
#define BS_ (B_*S_)

using bf16x8 = __attribute__((ext_vector_type(8))) short;
using f32x4  = __attribute__((ext_vector_type(4))) float;
using f32x16 = __attribute__((ext_vector_type(16))) float;

typedef const __attribute__((address_space(1))) unsigned int gu32;
typedef __attribute__((address_space(3))) unsigned int lu32;

static __device__ inline unsigned short f2bf(float a) {
  union { __hip_bfloat16 h; unsigned short u; } x;
  x.h = __float2bfloat16(a); return x.u;
}
static __device__ inline float bf16f(unsigned short u) {
  union { unsigned u32; float f; } x; x.u32 = (unsigned)u << 16; return x.f;
}
// HW packed f32->bf16 (RNE), 1 VALU op for 2 values
static __device__ inline unsigned pk2(float a, float b) {
  unsigned r;
  asm("v_cvt_pk_bf16_f32 %0, %1, %2" : "=v"(r) : "v"(a), "v"(b));
  return r;
}
static __device__ inline float ex2(float a) {
  return __builtin_amdgcn_exp2f(a);   // raw v_exp_f32
}

// ---------------------------------------------------------------------------
// MFMA GEMM: C = A @ W + bias, bf16 split-precision (unchanged).
// ---------------------------------------------------------------------------
template <int SPLIT, int BF16OUT>
__global__ __launch_bounds__(256) void gemm_mfma_kernel(
    const float* __restrict__ A, const float* __restrict__ W,
    const float* __restrict__ bias, void* __restrict__ Cv) {
  const int bn = blockIdx.x;      // 8
  const int bm = blockIdx.y;      // 64
  const int tid = threadIdx.x;
  const int wv = tid >> 6, lane = tid & 63;
  const int c = lane & 15, g = lane >> 4;

  __shared__ unsigned short As[SPLIT + 1][128][72];
  __shared__ unsigned short Wt[SPLIT + 1][64][72];

  f32x4 acc[2][4];
#pragma unroll
  for (int rt = 0; rt < 2; ++rt)
#pragma unroll
    for (int ds = 0; ds < 4; ++ds) acc[rt][ds] = f32x4{0.f, 0.f, 0.f, 0.f};

  const int arow = tid >> 1, ah = (tid & 1) * 32;
  const int wn = tid & 63, wkg = (tid >> 6) * 16;

  for (int k0 = 0; k0 < D_; k0 += 64) {
    float af[32];
    const float* ag = A + ((size_t)(bm * 128 + arow)) * D_ + k0 + ah;
#pragma unroll
    for (int i = 0; i < 8; ++i) *(float4*)&af[i * 4] = *(const float4*)(ag + i * 4);
    float wf[16];
    const float* wg = W + (size_t)(k0 + wkg) * D_ + bn * 64 + wn;
#pragma unroll
    for (int i = 0; i < 16; ++i) wf[i] = wg[(size_t)i * D_];

    __syncthreads();
#pragma unroll
    for (int grp = 0; grp < 4; ++grp) {
      unsigned h[4], l[4];
#pragma unroll
      for (int p = 0; p < 4; ++p) {
        float f0 = af[grp * 8 + p * 2], f1 = af[grp * 8 + p * 2 + 1];
        h[p] = pk2(f0, f1);
        if constexpr (SPLIT)
          l[p] = pk2(f0 - bf16f((unsigned short)(h[p] & 0xffff)),
                     f1 - bf16f((unsigned short)(h[p] >> 16)));
      }
      uint4 uh; uh.x = h[0]; uh.y = h[1]; uh.z = h[2]; uh.w = h[3];
      *(uint4*)&As[0][arow][ah + grp * 8] = uh;
      if constexpr (SPLIT) {
        uint4 ul; ul.x = l[0]; ul.y = l[1]; ul.z = l[2]; ul.w = l[3];
        *(uint4*)&As[1][arow][ah + grp * 8] = ul;
      }
    }
#pragma unroll
    for (int grp = 0; grp < 2; ++grp) {
      unsigned h[4], l[4];
#pragma unroll
      for (int p = 0; p < 4; ++p) {
        float f0 = wf[grp * 8 + p * 2], f1 = wf[grp * 8 + p * 2 + 1];
        h[p] = pk2(f0, f1);
        if constexpr (SPLIT)
          l[p] = pk2(f0 - bf16f((unsigned short)(h[p] & 0xffff)),
                     f1 - bf16f((unsigned short)(h[p] >> 16)));
      }
      uint4 uh; uh.x = h[0]; uh.y = h[1]; uh.z = h[2]; uh.w = h[3];
      *(uint4*)&Wt[0][wn][wkg + grp * 8] = uh;
      if constexpr (SPLIT) {
        uint4 ul; ul.x = l[0]; ul.y = l[1]; ul.z = l[2]; ul.w = l[3];
        *(uint4*)&Wt[1][wn][wkg + grp * 8] = ul;
      }
    }
    __syncthreads();

#pragma unroll
    for (int ksub = 0; ksub < 2; ++ksub) {
      bf16x8 bh[2], bl[2];
#pragma unroll
      for (int rt = 0; rt < 2; ++rt) {
        bh[rt] = *(const bf16x8*)&As[0][wv * 32 + rt * 16 + c][ksub * 32 + g * 8];
        if constexpr (SPLIT)
          bl[rt] = *(const bf16x8*)&As[1][wv * 32 + rt * 16 + c][ksub * 32 + g * 8];
      }
#pragma unroll
      for (int ds = 0; ds < 4; ++ds) {
        bf16x8 ah_ = *(const bf16x8*)&Wt[0][ds * 16 + c][ksub * 32 + g * 8];
#pragma unroll
        for (int rt = 0; rt < 2; ++rt)
          acc[rt][ds] = __builtin_amdgcn_mfma_f32_16x16x32_bf16(ah_, bh[rt], acc[rt][ds], 0, 0, 0);
        if constexpr (SPLIT) {
          bf16x8 al_ = *(const bf16x8*)&Wt[1][ds * 16 + c][ksub * 32 + g * 8];
#pragma unroll
          for (int rt = 0; rt < 2; ++rt) {
            acc[rt][ds] = __builtin_amdgcn_mfma_f32_16x16x32_bf16(ah_, bl[rt], acc[rt][ds], 0, 0, 0);
            acc[rt][ds] = __builtin_amdgcn_mfma_f32_16x16x32_bf16(al_, bh[rt], acc[rt][ds], 0, 0, 0);
          }
        }
      }
    }
  }

#pragma unroll
  for (int rt = 0; rt < 2; ++rt) {
    const size_t m = (size_t)bm * 128 + wv * 32 + rt * 16 + c;
#pragma unroll
    for (int ds = 0; ds < 4; ++ds) {
      const int n = bn * 64 + ds * 16 + 4 * g;
      float4 bv = *(const float4*)&bias[n];
      float o0 = acc[rt][ds][0] + bv.x, o1 = acc[rt][ds][1] + bv.y;
      float o2 = acc[rt][ds][2] + bv.z, o3 = acc[rt][ds][3] + bv.w;
      if constexpr (BF16OUT) {
        uint2 p; p.x = pk2(o0, o1); p.y = pk2(o2, o3);
        *(uint2*)((unsigned short*)Cv + m * D_ + n) = p;
      } else {
        float4 o; o.x = o0; o.y = o1; o.z = o2; o.w = o3;
        *(float4*)((float*)Cv + m * D_ + n) = o;
      }
    }
  }
}

// ---------------------------------------------------------------------------
// Causal local-window (L=5) softmax pooling; f32 in, bf16 out (scaled).
// ---------------------------------------------------------------------------
__global__ __launch_bounds__(256) void local_pool_kernel(
    const float* __restrict__ x, unsigned short* __restrict__ out,
    float oscale) {
  const int gtid = blockIdx.x * 256 + threadIdx.x;
  const int wave = gtid >> 6;
  const int lane = gtid & 63;
  if (wave >= BS_) return;
  const int b = wave / S_, s = wave % S_;
  const float* xrow = x + ((size_t)b * S_ + s) * D_;
  const int d0 = lane * 8;
  float xi[8];
  *(float4*)&xi[0] = *(const float4*)&xrow[d0];
  *(float4*)&xi[4] = *(const float4*)&xrow[d0 + 4];
  float win[5][8];
  float sc[5];
#pragma unroll
  for (int j = 0; j < 5; ++j) {
    int src = s - 4 + j;
    float part = 0.f;
    if (src >= 0) {
      const float* wr = x + ((size_t)b * S_ + src) * D_;
      *(float4*)&win[j][0] = *(const float4*)&wr[d0];
      *(float4*)&win[j][4] = *(const float4*)&wr[d0 + 4];
#pragma unroll
      for (int t = 0; t < 8; ++t) part += xi[t] * win[j][t];
    } else {
#pragma unroll
      for (int t = 0; t < 8; ++t) win[j][t] = 0.f;
    }
    sc[j] = part;
  }
#pragma unroll
  for (int off = 1; off < 64; off <<= 1) {
#pragma unroll
    for (int j = 0; j < 5; ++j) sc[j] += __shfl_xor(sc[j], off, 64);
  }
  const float scale = 0.04419417382415922f;  // 1/sqrt(512)
  float m = sc[0] * scale;
#pragma unroll
  for (int j = 1; j < 5; ++j) m = fmaxf(m, sc[j] * scale);
  float w[5], lsum = 0.f;
#pragma unroll
  for (int j = 0; j < 5; ++j) { w[j] = expf(sc[j] * scale - m); lsum += w[j]; }
  const float inv = oscale / lsum;
  float o[8] = {};
#pragma unroll
  for (int j = 0; j < 5; ++j)
#pragma unroll
    for (int t = 0; t < 8; ++t) o[t] += w[j] * win[j][t];
  unsigned short* orow = out + ((size_t)b * S_ + s) * D_;
  uint4 pk;
  pk.x = pk2(o[0] * inv, o[1] * inv);
  pk.y = pk2(o[2] * inv, o[3] * inv);
  pk.z = pk2(o[4] * inv, o[5] * inv);
  pk.w = pk2(o[6] * inv, o[7] * inv);
  *(uint4*)&orow[d0] = pk;
}

// ---------------------------------------------------------------------------
// 32x32x16 MFMA flash attention, 2-way KV-split.
// Identical to round 6 except __launch_bounds__(256, 3): 3 waves/SIMD needs
// <=170 VGPR/wave (512-reg SIMD pool), which fits the true ~140-reg live set
// with NO spill; (256,4)'s 128-reg cap forced ~38MB of scratch round-trips.
// Occupancy measured at (256,4) was ~38% anyway, so we lose nothing.
// ---------------------------------------------------------------------------
__global__ __launch_bounds__(256, 3) void attn_mfma32_kernel(
    const unsigned short* __restrict__ q, const unsigned short* __restrict__ k,
    const unsigned short* __restrict__ v, float* __restrict__ x) {
  const int bid = (blockIdx.x & 7) * 128 + (blockIdx.x >> 3);  // XCD swizzle
  const int qb = bid & 31;             // 64-row q-block
  const int h  = (bid >> 5) & 7;
  const int b  = bid >> 8;
  const int tid = threadIdx.x;
  const int w = tid >> 6, l = tid & 63;
  const int ql = l & 31, hi = l >> 5;
  const int wq = w & 1, wh = w >> 1;

  __shared__ __align__(16) unsigned short TileMem[4][64 * 64];  // K0,K1,V0,V1
  char* KsB = (char*)TileMem[wh];
  char* VtB = (char*)TileMem[2 + wh];

  // Q fragments (B-operand): Qf[f][j] = q[qrow][16f + 8hi + j]
  bf16x8 Qf[4];
  {
    const unsigned short* qg =
        q + ((size_t)b * S_ + qb * 64 + wq * 32 + ql) * D_ + h * 64 + hi * 8;
#pragma unroll
    for (int f = 0; f < 4; ++f) Qf[f] = *(const bf16x8*)(qg + f * 16);
  }

  f32x16 accO[2] = {};           // O^T: [d-tile 32][q]
  float m = -INFINITY, lsum = 0.f;

  // ---- K staging (async): wave (wh, wq) stages rows wq*32..+31 of half wh ----
  const int lr8 = l >> 3, lc = l & 7;
  const unsigned short* kgl =
      k + ((size_t)b * S_ + wh * 1024 + wq * 32 + lr8) * D_ + h * 64 + ((lc ^ lr8) << 3);
  char* ldsK = (char*)TileMem[wh] + wq * 4096;   // + j*1024 per instr

  // ---- V staging: 128 threads per half (sh == wh for the half's waves) ----
  const int sh = tid >> 7, st = tid & 127;
  const int vd = st & 63, vg2 = (st >> 6) & 1;
  const unsigned short* vg0 =
      v + ((size_t)b * S_ + sh * 1024 + vg2 * 32) * D_ + h * 64 + vd;
  char* VtS = (char*)TileMem[2 + sh];
  const int vb0 = vd * 128 + vg2 * 64, vmask = (vd & 7) << 4;

  // prefetch V tile 0 (pairs of keys packed into dwords)
  unsigned rvp[16];
#pragma unroll
  for (int i = 0; i < 16; ++i) {
    unsigned lo = vg0[(size_t)(2 * i) * D_];
    unsigned hs = vg0[(size_t)(2 * i + 1) * D_];
    rvp[i] = lo | (hs << 16);
  }

  for (int kt = 0; kt < 16; ++kt) {
    __syncthreads();                      // prev compute done reading LDS
    {  // K: async global->LDS, linear dest, pre-swizzled source
      const unsigned short* kp = kgl + (size_t)kt * 64 * D_;
#pragma unroll
      for (int j = 0; j < 4; ++j)
        __builtin_amdgcn_global_load_lds((gu32*)(kp + (size_t)j * 8 * D_),
                                         (lu32*)(ldsK + j * 1024), 16, 0, 0);
    }
    // V: write prefetched regs (XOR-swizzled ds_write_b128)
#pragma unroll
    for (int i = 0; i < 4; ++i) {
      uint4 t_;
      t_.x = rvp[4 * i]; t_.y = rvp[4 * i + 1];
      t_.z = rvp[4 * i + 2]; t_.w = rvp[4 * i + 3];
      *(uint4*)(VtS + ((vb0 + i * 16) ^ vmask)) = t_;
    }
    __syncthreads();                      // drains vmcnt (K) + lgkm (V)
    if (kt + 1 < 16) {                    // prefetch next V tile
      const size_t koff = (size_t)(kt + 1) * 64 * D_;
#pragma unroll
      for (int i = 0; i < 16; ++i) {
        unsigned lo = vg0[koff + (size_t)(2 * i) * D_];
        unsigned hs = vg0[koff + (size_t)(2 * i + 1) * D_];
        rvp[i] = lo | (hs << 16);
      }
    }

    // ---- QK^T: two 32-key subtiles ----
    f32x16 sA = {}, sB = {};
    __builtin_amdgcn_s_setprio(1);
#pragma unroll
    for (int f = 0; f < 4; ++f) {
      bf16x8 a0 = *(const bf16x8*)(KsB + ((ql * 128 + f * 32 + hi * 16) ^ ((ql & 7) << 4)));
      bf16x8 a1 = *(const bf16x8*)(KsB + (((ql + 32) * 128 + f * 32 + hi * 16) ^ ((ql & 7) << 4)));
      sA = __builtin_amdgcn_mfma_f32_32x32x16_bf16(a0, Qf[f], sA, 0, 0, 0);
      sB = __builtin_amdgcn_mfma_f32_32x32x16_bf16(a1, Qf[f], sB, 0, 0, 0);
    }
    __builtin_amdgcn_s_setprio(0);

    // ---- tree max, defer-max THR=10 ----
    float mx[8];
#pragma unroll
    for (int r = 0; r < 8; ++r)
      mx[r] = fmaxf(fmaxf(sA[r], sA[r + 8]), fmaxf(sB[r], sB[r + 8]));
    mx[0] = fmaxf(mx[0], mx[4]); mx[1] = fmaxf(mx[1], mx[5]);
    mx[2] = fmaxf(mx[2], mx[6]); mx[3] = fmaxf(mx[3], mx[7]);
    mx[0] = fmaxf(fmaxf(mx[0], mx[1]), fmaxf(mx[2], mx[3]));
    const float mt = fmaxf(mx[0], __shfl_xor(mx[0], 32, 64));
    if (!__all(mt <= m + 10.0f)) {
      const float mn = fmaxf(m, mt);
      const float corr = ex2(m - mn);
      m = mn;
      lsum *= corr;
#pragma unroll
      for (int dt = 0; dt < 2; ++dt)
#pragma unroll
        for (int r = 0; r < 16; ++r) accO[dt][r] *= corr;
    }

    // ---- fused exp2 -> pack -> pairwise sum (no pA/pB arrays) ----
    unsigned WA[8], WB[8];
    float s0 = 0.f, s1 = 0.f, s2 = 0.f, s3 = 0.f;
#pragma unroll
    for (int t = 0; t < 4; ++t) {
      float a0 = ex2(sA[4 * t + 0] - m), a1 = ex2(sA[4 * t + 1] - m);
      float a2 = ex2(sA[4 * t + 2] - m), a3 = ex2(sA[4 * t + 3] - m);
      WA[2 * t] = pk2(a0, a1); WA[2 * t + 1] = pk2(a2, a3);
      s0 += a0 + a1; s1 += a2 + a3;
      float b0 = ex2(sB[4 * t + 0] - m), b1 = ex2(sB[4 * t + 1] - m);
      float b2 = ex2(sB[4 * t + 2] - m), b3 = ex2(sB[4 * t + 3] - m);
      WB[2 * t] = pk2(b0, b1); WB[2 * t + 1] = pk2(b2, b3);
      s2 += b0 + b1; s3 += b2 + b3;
    }
    lsum += (s0 + s1) + (s2 + s3);

    // ---- PV: 4 key-chunks x 2 d-tiles ----
#pragma unroll
    for (int kc = 0; kc < 4; ++kc) {
      unsigned w0 = (kc < 2) ? WA[(kc & 1) * 4 + 0] : WB[(kc & 1) * 4 + 0];
      unsigned w1 = (kc < 2) ? WA[(kc & 1) * 4 + 1] : WB[(kc & 1) * 4 + 1];
      unsigned w2 = (kc < 2) ? WA[(kc & 1) * 4 + 2] : WB[(kc & 1) * 4 + 2];
      unsigned w3 = (kc < 2) ? WA[(kc & 1) * 4 + 3] : WB[(kc & 1) * 4 + 3];
      asm volatile("v_permlane32_swap_b32 %0, %1" : "+v"(w0), "+v"(w2));
      asm volatile("v_permlane32_swap_b32 %0, %1" : "+v"(w1), "+v"(w3));
      union { unsigned u[4]; bf16x8 v8; } pb;
      pb.u[0] = w0; pb.u[1] = w1; pb.u[2] = w2; pb.u[3] = w3;
      __builtin_amdgcn_s_setprio(1);
#pragma unroll
      for (int dt = 0; dt < 2; ++dt) {
        const int vrow = dt * 32 + ql;
        bf16x8 va = *(const bf16x8*)(VtB + ((vrow * 128 + kc * 32 + hi * 16) ^ ((ql & 7) << 4)));
        accO[dt] = __builtin_amdgcn_mfma_f32_32x32x16_bf16(va, pb.v8, accO[dt], 0, 0, 0);
      }
      __builtin_amdgcn_s_setprio(0);
    }
  }

  // ---- cross-wave combine (halves share q-subtile) ----
  float lw = lsum + __shfl_xor(lsum, 32, 64);
  __syncthreads();                        // all waves done with tiles
  float* cb = (float*)TileMem + (size_t)wq * 2176 + (size_t)l * 34;
  if (wh == 1) {
#pragma unroll
    for (int dt = 0; dt < 2; ++dt)
#pragma unroll
      for (int r = 0; r < 16; ++r) cb[dt * 16 + r] = accO[dt][r];
    cb[32] = m; cb[33] = lw;
  }
  __syncthreads();
  if (wh == 0) {
    const float m1 = cb[32], l1 = cb[33];
    const float mn = fmaxf(m, m1);
    const float a0 = ex2(m - mn), a1 = ex2(m1 - mn);
    const float inv = 1.f / (lw * a0 + l1 * a1);
    float* xrow = x + ((size_t)b * S_ + qb * 64 + wq * 32 + ql) * D_ + h * 64;
#pragma unroll
    for (int dt = 0; dt < 2; ++dt)
#pragma unroll
      for (int g0 = 0; g0 < 4; ++g0) {
        float4 o;
        o.x = (accO[dt][4 * g0 + 0] * a0 + cb[dt * 16 + 4 * g0 + 0] * a1) * inv;
        o.y = (accO[dt][4 * g0 + 1] * a0 + cb[dt * 16 + 4 * g0 + 1] * a1) * inv;
        o.z = (accO[dt][4 * g0 + 2] * a0 + cb[dt * 16 + 4 * g0 + 2] * a1) * inv;
        o.w = (accO[dt][4 * g0 + 3] * a0 + cb[dt * 16 + 4 * g0 + 3] * a1) * inv;
        *(float4*)&xrow[dt * 32 + hi * 4 + g0 * 8] = o;
      }
  }
}

// ---------------------------------------------------------------------------
extern "C" void kernel_launch(void* const* d_in, const int* in_sizes, int n_in,
                              void* d_out, int out_size, void* d_ws, size_t ws_size,
                              hipStream_t stream) {
  const float* query = (const float*)d_in[0];
  const float* key   = (const float*)d_in[1];
  const float* value = (const float*)d_in[2];
  const float* W_fk = (const float*)d_in[4];
  const float* b_fk = (const float*)d_in[5];
  const float* W0   = (const float*)d_in[6];
  const float* b0   = (const float*)d_in[7];
  const float* Wout = (const float*)d_in[8];
  const float* bout = (const float*)d_in[9];
  float* out = (float*)d_out;

  char* ws = (char*)d_ws;
  float* kfk_f32   = (float*)ws;                       // 16MB @ 0 (later q_bf16)
  float* x_f32     = (float*)(ws + (16u << 20));       // 16MB @ 16MB
  unsigned short* k_bf16 = (unsigned short*)(ws + (32u << 20));  // 8MB @ 32MB
  unsigned short* v_bf16 = (unsigned short*)(ws + (40u << 20));  // 8MB @ 40MB
  unsigned short* q_bf16 = (unsigned short*)ws;        // overlays kfk after use

  dim3 mgrid(D_ / 64, BS_ / 128);
  dim3 pgrid(BS_ * 64 / 256);
  // 1/sqrt(dk) * log2(e): softmax runs in exp2 domain
  const float qscale = 0.125f * 1.4426950408889634f;

  gemm_mfma_kernel<1, 0><<<mgrid, 256, 0, stream>>>(key, W_fk, b_fk, kfk_f32);
  local_pool_kernel<<<pgrid, 256, 0, stream>>>(kfk_f32, k_bf16, 1.0f);
  gemm_mfma_kernel<0, 1><<<mgrid, 256, 0, stream>>>(value, W0, b0, v_bf16);
  local_pool_kernel<<<pgrid, 256, 0, stream>>>(query, q_bf16, qscale);
  attn_mfma32_kernel<<<dim3(B_ * H_ * (S_ / 64)), 256, 0, stream>>>(q_bf16, k_bf16, v_bf16, x_f32);
  gemm_mfma_kernel<1, 0><<<mgrid, 256, 0, stream>>>(x_f32, Wout, bout, out);
}

// Round 8
// 171.514 us; speedup vs baseline: 1.5387x; 1.0721x over previous
//
#include <hip/hip_runtime.h>
#include <hip/hip_bf16.h>
#include <math.h>

#define B_  4
#define S_  2048
#define D_  512
#define H_  8
#define DK_ 64
#define BS_ (B_*S_)

using bf16x8 = __attribute__((ext_vector_type(8))) short;
using f32x4  = __attribute__((ext_vector_type(4))) float;
using f32x16 = __attribute__((ext_vector_type(16))) float;

typedef const __attribute__((address_space(1))) unsigned int gu32;
typedef __attribute__((address_space(3))) unsigned int lu32;

static __device__ inline unsigned short f2bf(float a) {
  union { __hip_bfloat16 h; unsigned short u; } x;
  x.h = __float2bfloat16(a); return x.u;
}
static __device__ inline float bf16f(unsigned short u) {
  union { unsigned u32; float f; } x; x.u32 = (unsigned)u << 16; return x.f;
}
// HW packed f32->bf16 (RNE), 1 VALU op for 2 values
static __device__ inline unsigned pk2(float a, float b) {
  unsigned r;
  asm("v_cvt_pk_bf16_f32 %0, %1, %2" : "=v"(r) : "v"(a), "v"(b));
  return r;
}
static __device__ inline float ex2(float a) {
  return __builtin_amdgcn_exp2f(a);   // raw v_exp_f32
}

// ---------------------------------------------------------------------------
// MFMA GEMM: C = A @ W + bias, bf16 split-precision.
// OUTMODE: 0 = f32 row-major, 1 = bf16 row-major, 2 = bf16 V^T [b][n][s]
// (mode 2 feeds attention's V staging: V^T rows are contiguous in s, so the
// attention kernel can stage V with global_load_lds exactly like K).
// ---------------------------------------------------------------------------
template <int SPLIT, int OUTMODE>
__global__ __launch_bounds__(256) void gemm_mfma_kernel(
    const float* __restrict__ A, const float* __restrict__ W,
    const float* __restrict__ bias, void* __restrict__ Cv) {
  const int bn = blockIdx.x;      // 8
  const int bm = blockIdx.y;      // 64
  const int tid = threadIdx.x;
  const int wv = tid >> 6, lane = tid & 63;
  const int c = lane & 15, g = lane >> 4;

  __shared__ unsigned short As[SPLIT + 1][128][72];
  __shared__ unsigned short Wt[SPLIT + 1][64][72];

  f32x4 acc[2][4];
#pragma unroll
  for (int rt = 0; rt < 2; ++rt)
#pragma unroll
    for (int ds = 0; ds < 4; ++ds) acc[rt][ds] = f32x4{0.f, 0.f, 0.f, 0.f};

  const int arow = tid >> 1, ah = (tid & 1) * 32;
  const int wn = tid & 63, wkg = (tid >> 6) * 16;

  for (int k0 = 0; k0 < D_; k0 += 64) {
    float af[32];
    const float* ag = A + ((size_t)(bm * 128 + arow)) * D_ + k0 + ah;
#pragma unroll
    for (int i = 0; i < 8; ++i) *(float4*)&af[i * 4] = *(const float4*)(ag + i * 4);
    float wf[16];
    const float* wg = W + (size_t)(k0 + wkg) * D_ + bn * 64 + wn;
#pragma unroll
    for (int i = 0; i < 16; ++i) wf[i] = wg[(size_t)i * D_];

    __syncthreads();
#pragma unroll
    for (int grp = 0; grp < 4; ++grp) {
      unsigned h[4], l[4];
#pragma unroll
      for (int p = 0; p < 4; ++p) {
        float f0 = af[grp * 8 + p * 2], f1 = af[grp * 8 + p * 2 + 1];
        h[p] = pk2(f0, f1);
        if constexpr (SPLIT)
          l[p] = pk2(f0 - bf16f((unsigned short)(h[p] & 0xffff)),
                     f1 - bf16f((unsigned short)(h[p] >> 16)));
      }
      uint4 uh; uh.x = h[0]; uh.y = h[1]; uh.z = h[2]; uh.w = h[3];
      *(uint4*)&As[0][arow][ah + grp * 8] = uh;
      if constexpr (SPLIT) {
        uint4 ul; ul.x = l[0]; ul.y = l[1]; ul.z = l[2]; ul.w = l[3];
        *(uint4*)&As[1][arow][ah + grp * 8] = ul;
      }
    }
#pragma unroll
    for (int grp = 0; grp < 2; ++grp) {
      unsigned h[4], l[4];
#pragma unroll
      for (int p = 0; p < 4; ++p) {
        float f0 = wf[grp * 8 + p * 2], f1 = wf[grp * 8 + p * 2 + 1];
        h[p] = pk2(f0, f1);
        if constexpr (SPLIT)
          l[p] = pk2(f0 - bf16f((unsigned short)(h[p] & 0xffff)),
                     f1 - bf16f((unsigned short)(h[p] >> 16)));
      }
      uint4 uh; uh.x = h[0]; uh.y = h[1]; uh.z = h[2]; uh.w = h[3];
      *(uint4*)&Wt[0][wn][wkg + grp * 8] = uh;
      if constexpr (SPLIT) {
        uint4 ul; ul.x = l[0]; ul.y = l[1]; ul.z = l[2]; ul.w = l[3];
        *(uint4*)&Wt[1][wn][wkg + grp * 8] = ul;
      }
    }
    __syncthreads();

#pragma unroll
    for (int ksub = 0; ksub < 2; ++ksub) {
      bf16x8 bh[2], bl[2];
#pragma unroll
      for (int rt = 0; rt < 2; ++rt) {
        bh[rt] = *(const bf16x8*)&As[0][wv * 32 + rt * 16 + c][ksub * 32 + g * 8];
        if constexpr (SPLIT)
          bl[rt] = *(const bf16x8*)&As[1][wv * 32 + rt * 16 + c][ksub * 32 + g * 8];
      }
#pragma unroll
      for (int ds = 0; ds < 4; ++ds) {
        bf16x8 ah_ = *(const bf16x8*)&Wt[0][ds * 16 + c][ksub * 32 + g * 8];
#pragma unroll
        for (int rt = 0; rt < 2; ++rt)
          acc[rt][ds] = __builtin_amdgcn_mfma_f32_16x16x32_bf16(ah_, bh[rt], acc[rt][ds], 0, 0, 0);
        if constexpr (SPLIT) {
          bf16x8 al_ = *(const bf16x8*)&Wt[1][ds * 16 + c][ksub * 32 + g * 8];
#pragma unroll
          for (int rt = 0; rt < 2; ++rt) {
            acc[rt][ds] = __builtin_amdgcn_mfma_f32_16x16x32_bf16(ah_, bl[rt], acc[rt][ds], 0, 0, 0);
            acc[rt][ds] = __builtin_amdgcn_mfma_f32_16x16x32_bf16(al_, bh[rt], acc[rt][ds], 0, 0, 0);
          }
        }
      }
    }
  }

#pragma unroll
  for (int rt = 0; rt < 2; ++rt) {
    const size_t m = (size_t)bm * 128 + wv * 32 + rt * 16 + c;
#pragma unroll
    for (int ds = 0; ds < 4; ++ds) {
      const int n = bn * 64 + ds * 16 + 4 * g;
      float4 bv = *(const float4*)&bias[n];
      float o0 = acc[rt][ds][0] + bv.x, o1 = acc[rt][ds][1] + bv.y;
      float o2 = acc[rt][ds][2] + bv.z, o3 = acc[rt][ds][3] + bv.w;
      if constexpr (OUTMODE == 1) {
        uint2 p; p.x = pk2(o0, o1); p.y = pk2(o2, o3);
        *(uint2*)((unsigned short*)Cv + m * D_ + n) = p;
      } else if constexpr (OUTMODE == 2) {
        // V^T: [b][n][s]; b = m>>11, s = m&2047 (block never crosses batch)
        const unsigned u01 = pk2(o0, o1), u23 = pk2(o2, o3);
        unsigned short* base =
            (unsigned short*)Cv + ((size_t)(m >> 11) * D_ + n) * (size_t)S_ + (m & 2047);
        base[0]        = (unsigned short)u01;
        base[S_]       = (unsigned short)(u01 >> 16);
        base[2 * S_]   = (unsigned short)u23;
        base[3 * S_]   = (unsigned short)(u23 >> 16);
      } else {
        float4 o; o.x = o0; o.y = o1; o.z = o2; o.w = o3;
        *(float4*)((float*)Cv + m * D_ + n) = o;
      }
    }
  }
}

// ---------------------------------------------------------------------------
// Causal local-window (L=5) softmax pooling; f32 in, bf16 out (scaled).
// ---------------------------------------------------------------------------
__global__ __launch_bounds__(256) void local_pool_kernel(
    const float* __restrict__ x, unsigned short* __restrict__ out,
    float oscale) {
  const int gtid = blockIdx.x * 256 + threadIdx.x;
  const int wave = gtid >> 6;
  const int lane = gtid & 63;
  if (wave >= BS_) return;
  const int b = wave / S_, s = wave % S_;
  const float* xrow = x + ((size_t)b * S_ + s) * D_;
  const int d0 = lane * 8;
  float xi[8];
  *(float4*)&xi[0] = *(const float4*)&xrow[d0];
  *(float4*)&xi[4] = *(const float4*)&xrow[d0 + 4];
  float win[5][8];
  float sc[5];
#pragma unroll
  for (int j = 0; j < 5; ++j) {
    int src = s - 4 + j;
    float part = 0.f;
    if (src >= 0) {
      const float* wr = x + ((size_t)b * S_ + src) * D_;
      *(float4*)&win[j][0] = *(const float4*)&wr[d0];
      *(float4*)&win[j][4] = *(const float4*)&wr[d0 + 4];
#pragma unroll
      for (int t = 0; t < 8; ++t) part += xi[t] * win[j][t];
    } else {
#pragma unroll
      for (int t = 0; t < 8; ++t) win[j][t] = 0.f;
    }
    sc[j] = part;
  }
#pragma unroll
  for (int off = 1; off < 64; off <<= 1) {
#pragma unroll
    for (int j = 0; j < 5; ++j) sc[j] += __shfl_xor(sc[j], off, 64);
  }
  const float scale = 0.04419417382415922f;  // 1/sqrt(512)
  float m = sc[0] * scale;
#pragma unroll
  for (int j = 1; j < 5; ++j) m = fmaxf(m, sc[j] * scale);
  float w[5], lsum = 0.f;
#pragma unroll
  for (int j = 0; j < 5; ++j) { w[j] = expf(sc[j] * scale - m); lsum += w[j]; }
  const float inv = oscale / lsum;
  float o[8] = {};
#pragma unroll
  for (int j = 0; j < 5; ++j)
#pragma unroll
    for (int t = 0; t < 8; ++t) o[t] += w[j] * win[j][t];
  unsigned short* orow = out + ((size_t)b * S_ + s) * D_;
  uint4 pk;
  pk.x = pk2(o[0] * inv, o[1] * inv);
  pk.y = pk2(o[2] * inv, o[3] * inv);
  pk.z = pk2(o[4] * inv, o[5] * inv);
  pk.w = pk2(o[6] * inv, o[7] * inv);
  *(uint4*)&orow[d0] = pk;
}

// ---------------------------------------------------------------------------
// 32x32x16 MFMA flash attention, 2-way KV-split, double-buffered async LDS.
// Block = 4 waves: wave (wq, wh) = q-subtile wq over KV half wh (16 tiles).
// BOTH K and V^T are staged via global_load_lds (async, zero staging VGPRs):
// V was pre-transposed by the v-GEMM to [b][d][s], so its tile rows (d) are
// contiguous in s exactly like K's rows are contiguous in d.
// Swizzle rule (both): linear LDS dest + inverse-swizzled per-lane global
// source chunk (l&7)^(l>>3); reads XOR byte addr with ((row&7)<<4).
// T3 minimal 2-phase pipeline: ISSUE(t+1 -> buf^1); compute(buf);
// s_waitcnt vmcnt(0); s_barrier. The t+1 loads land under compute t.
// LDS = 2 bufs x (K 16KB + V 16KB) = 64KB -> 2 blocks/CU.
// ---------------------------------------------------------------------------
__global__ __launch_bounds__(256, 2) void attn_mfma32_kernel(
    const unsigned short* __restrict__ q, const unsigned short* __restrict__ k,
    const unsigned short* __restrict__ vt, float* __restrict__ x) {
  const int bid = (blockIdx.x & 7) * 128 + (blockIdx.x >> 3);  // XCD swizzle
  const int qb = bid & 31;             // 64-row q-block
  const int h  = (bid >> 5) & 7;
  const int b  = bid >> 8;
  const int tid = threadIdx.x;
  const int w = tid >> 6, l = tid & 63;
  const int ql = l & 31, hi = l >> 5;
  const int wq = w & 1, wh = w >> 1;

  // [buf][0=K,1=V][half][64x64]
  __shared__ __align__(16) unsigned short L[2][2][2][4096];

  // Q fragments (B-operand): Qf[f][j] = q[qrow][16f + 8hi + j]
  bf16x8 Qf[4];
  {
    const unsigned short* qg =
        q + ((size_t)b * S_ + qb * 64 + wq * 32 + ql) * D_ + h * 64 + hi * 8;
#pragma unroll
    for (int f = 0; f < 4; ++f) Qf[f] = *(const bf16x8*)(qg + f * 16);
  }

  f32x16 accO[2] = {};           // O^T: [d-tile 32][q]
  float m = -INFINITY, lsum = 0.f;

  // staging sources (lane l: row lr8 within 8-row group, chunk lc^lr8)
  const int lr8 = l >> 3, lc = l & 7;
  const unsigned short* kg =
      k + ((size_t)b * S_ + wh * 1024 + wq * 32 + lr8) * D_ + h * 64 + ((lc ^ lr8) << 3);
  const unsigned short* vg =
      vt + ((size_t)b * D_ + h * 64 + wq * 32 + lr8) * (size_t)S_ + wh * 1024 + ((lc ^ lr8) << 3);

  auto ISSUE = [&](int t, int bf) {
    const unsigned short* kp = kg + (size_t)t * 64 * D_;
    const unsigned short* vp = vg + t * 64;
    char* dk = (char*)&L[bf][0][wh][0] + wq * 4096;
    char* dv = (char*)&L[bf][1][wh][0] + wq * 4096;
#pragma unroll
    for (int j = 0; j < 4; ++j) {
      __builtin_amdgcn_global_load_lds((gu32*)(kp + (size_t)j * 8 * D_),
                                       (lu32*)(dk + j * 1024), 16, 0, 0);
      __builtin_amdgcn_global_load_lds((gu32*)(vp + (size_t)j * 8 * S_),
                                       (lu32*)(dv + j * 1024), 16, 0, 0);
    }
  };

  // prologue: tile 0
  ISSUE(0, 0);
  asm volatile("s_waitcnt vmcnt(0)" ::: "memory");
  __builtin_amdgcn_s_barrier();
  __builtin_amdgcn_sched_barrier(0);

  int cur = 0;
  for (int kt = 0; kt < 16; ++kt) {
    if (kt + 1 < 16) ISSUE(kt + 1, cur ^ 1);   // lands under this tile's compute
    __builtin_amdgcn_sched_barrier(0);
    const char* KsB = (const char*)&L[cur][0][wh][0];
    const char* VtB = (const char*)&L[cur][1][wh][0];

    // ---- QK^T: two 32-key subtiles ----
    f32x16 sA = {}, sB = {};
    __builtin_amdgcn_s_setprio(1);
#pragma unroll
    for (int f = 0; f < 4; ++f) {
      bf16x8 a0 = *(const bf16x8*)(KsB + ((ql * 128 + f * 32 + hi * 16) ^ ((ql & 7) << 4)));
      bf16x8 a1 = *(const bf16x8*)(KsB + (((ql + 32) * 128 + f * 32 + hi * 16) ^ ((ql & 7) << 4)));
      sA = __builtin_amdgcn_mfma_f32_32x32x16_bf16(a0, Qf[f], sA, 0, 0, 0);
      sB = __builtin_amdgcn_mfma_f32_32x32x16_bf16(a1, Qf[f], sB, 0, 0, 0);
    }
    __builtin_amdgcn_s_setprio(0);

    // ---- tree max, defer-max THR=10 ----
    float mx[8];
#pragma unroll
    for (int r = 0; r < 8; ++r)
      mx[r] = fmaxf(fmaxf(sA[r], sA[r + 8]), fmaxf(sB[r], sB[r + 8]));
    mx[0] = fmaxf(mx[0], mx[4]); mx[1] = fmaxf(mx[1], mx[5]);
    mx[2] = fmaxf(mx[2], mx[6]); mx[3] = fmaxf(mx[3], mx[7]);
    mx[0] = fmaxf(fmaxf(mx[0], mx[1]), fmaxf(mx[2], mx[3]));
    const float mt = fmaxf(mx[0], __shfl_xor(mx[0], 32, 64));
    if (!__all(mt <= m + 10.0f)) {
      const float mn = fmaxf(m, mt);
      const float corr = ex2(m - mn);
      m = mn;
      lsum *= corr;
#pragma unroll
      for (int dt = 0; dt < 2; ++dt)
#pragma unroll
        for (int r = 0; r < 16; ++r) accO[dt][r] *= corr;
    }

    // ---- fused exp2 -> pack -> pairwise sum ----
    unsigned WA[8], WB[8];
    float s0 = 0.f, s1 = 0.f, s2 = 0.f, s3 = 0.f;
#pragma unroll
    for (int t = 0; t < 4; ++t) {
      float a0 = ex2(sA[4 * t + 0] - m), a1 = ex2(sA[4 * t + 1] - m);
      float a2 = ex2(sA[4 * t + 2] - m), a3 = ex2(sA[4 * t + 3] - m);
      WA[2 * t] = pk2(a0, a1); WA[2 * t + 1] = pk2(a2, a3);
      s0 += a0 + a1; s1 += a2 + a3;
      float b0 = ex2(sB[4 * t + 0] - m), b1 = ex2(sB[4 * t + 1] - m);
      float b2 = ex2(sB[4 * t + 2] - m), b3 = ex2(sB[4 * t + 3] - m);
      WB[2 * t] = pk2(b0, b1); WB[2 * t + 1] = pk2(b2, b3);
      s2 += b0 + b1; s3 += b2 + b3;
    }
    lsum += (s0 + s1) + (s2 + s3);

    // ---- PV: 4 key-chunks x 2 d-tiles ----
#pragma unroll
    for (int kc = 0; kc < 4; ++kc) {
      unsigned w0 = (kc < 2) ? WA[(kc & 1) * 4 + 0] : WB[(kc & 1) * 4 + 0];
      unsigned w1 = (kc < 2) ? WA[(kc & 1) * 4 + 1] : WB[(kc & 1) * 4 + 1];
      unsigned w2 = (kc < 2) ? WA[(kc & 1) * 4 + 2] : WB[(kc & 1) * 4 + 2];
      unsigned w3 = (kc < 2) ? WA[(kc & 1) * 4 + 3] : WB[(kc & 1) * 4 + 3];
      asm volatile("v_permlane32_swap_b32 %0, %1" : "+v"(w0), "+v"(w2));
      asm volatile("v_permlane32_swap_b32 %0, %1" : "+v"(w1), "+v"(w3));
      union { unsigned u[4]; bf16x8 v8; } pb;
      pb.u[0] = w0; pb.u[1] = w1; pb.u[2] = w2; pb.u[3] = w3;
      __builtin_amdgcn_s_setprio(1);
#pragma unroll
      for (int dt = 0; dt < 2; ++dt) {
        const int vrow = dt * 32 + ql;
        bf16x8 va = *(const bf16x8*)(VtB + ((vrow * 128 + kc * 32 + hi * 16) ^ ((ql & 7) << 4)));
        accO[dt] = __builtin_amdgcn_mfma_f32_32x32x16_bf16(va, pb.v8, accO[dt], 0, 0, 0);
      }
      __builtin_amdgcn_s_setprio(0);
    }

    // ---- pipeline barrier: wait t+1 loads (landed under compute), sync ----
    asm volatile("s_waitcnt vmcnt(0)" ::: "memory");
    __builtin_amdgcn_s_barrier();
    __builtin_amdgcn_sched_barrier(0);
    cur ^= 1;
  }

  // ---- cross-wave combine (halves share q-subtile) ----
  float lw = lsum + __shfl_xor(lsum, 32, 64);
  __syncthreads();                        // all waves done with tiles
  float* cb = (float*)L + (size_t)wq * 2176 + (size_t)l * 34;
  if (wh == 1) {
#pragma unroll
    for (int dt = 0; dt < 2; ++dt)
#pragma unroll
      for (int r = 0; r < 16; ++r) cb[dt * 16 + r] = accO[dt][r];
    cb[32] = m; cb[33] = lw;
  }
  __syncthreads();
  if (wh == 0) {
    const float m1 = cb[32], l1 = cb[33];
    const float mn = fmaxf(m, m1);
    const float a0 = ex2(m - mn), a1 = ex2(m1 - mn);
    const float inv = 1.f / (lw * a0 + l1 * a1);
    float* xrow = x + ((size_t)b * S_ + qb * 64 + wq * 32 + ql) * D_ + h * 64;
#pragma unroll
    for (int dt = 0; dt < 2; ++dt)
#pragma unroll
      for (int g0 = 0; g0 < 4; ++g0) {
        float4 o;
        o.x = (accO[dt][4 * g0 + 0] * a0 + cb[dt * 16 + 4 * g0 + 0] * a1) * inv;
        o.y = (accO[dt][4 * g0 + 1] * a0 + cb[dt * 16 + 4 * g0 + 1] * a1) * inv;
        o.z = (accO[dt][4 * g0 + 2] * a0 + cb[dt * 16 + 4 * g0 + 2] * a1) * inv;
        o.w = (accO[dt][4 * g0 + 3] * a0 + cb[dt * 16 + 4 * g0 + 3] * a1) * inv;
        *(float4*)&xrow[dt * 32 + hi * 4 + g0 * 8] = o;
      }
  }
}

// ---------------------------------------------------------------------------
extern "C" void kernel_launch(void* const* d_in, const int* in_sizes, int n_in,
                              void* d_out, int out_size, void* d_ws, size_t ws_size,
                              hipStream_t stream) {
  const float* query = (const float*)d_in[0];
  const float* key   = (const float*)d_in[1];
  const float* value = (const float*)d_in[2];
  const float* W_fk = (const float*)d_in[4];
  const float* b_fk = (const float*)d_in[5];
  const float* W0   = (const float*)d_in[6];
  const float* b0   = (const float*)d_in[7];
  const float* Wout = (const float*)d_in[8];
  const float* bout = (const float*)d_in[9];
  float* out = (float*)d_out;

  char* ws = (char*)d_ws;
  float* kfk_f32   = (float*)ws;                       // 16MB @ 0 (later q_bf16)
  float* x_f32     = (float*)(ws + (16u << 20));       // 16MB @ 16MB
  unsigned short* k_bf16 = (unsigned short*)(ws + (32u << 20));  // 8MB @ 32MB
  unsigned short* vT_bf16 = (unsigned short*)(ws + (40u << 20)); // 8MB @ 40MB, [b][d][s]
  unsigned short* q_bf16 = (unsigned short*)ws;        // overlays kfk after use

  dim3 mgrid(D_ / 64, BS_ / 128);
  dim3 pgrid(BS_ * 64 / 256);
  // 1/sqrt(dk) * log2(e): softmax runs in exp2 domain
  const float qscale = 0.125f * 1.4426950408889634f;

  gemm_mfma_kernel<1, 0><<<mgrid, 256, 0, stream>>>(key, W_fk, b_fk, kfk_f32);
  local_pool_kernel<<<pgrid, 256, 0, stream>>>(kfk_f32, k_bf16, 1.0f);
  gemm_mfma_kernel<0, 2><<<mgrid, 256, 0, stream>>>(value, W0, b0, vT_bf16);
  local_pool_kernel<<<pgrid, 256, 0, stream>>>(query, q_bf16, qscale);
  attn_mfma32_kernel<<<dim3(B_ * H_ * (S_ / 64)), 256, 0, stream>>>(q_bf16, k_bf16, vT_bf16, x_f32);
  gemm_mfma_kernel<1, 0><<<mgrid, 256, 0, stream>>>(x_f32, Wout, bout, out);
}